// Round 1
// baseline (722.462 us; speedup 1.0000x reference)
//
#include <hip/hip_runtime.h>

#define N_  4096
#define C_  256
#define HI_ 64
#define HO_ 128

typedef __attribute__((ext_vector_type(8))) short bf16x8;
typedef __attribute__((ext_vector_type(4))) float f32x4;

// fp32 -> bf16 round-to-nearest-even (bit-level, no type dependency)
__device__ __forceinline__ short f2bf(float f) {
    union { float f; unsigned u; } v; v.f = f;
    unsigned r = v.u + 0x7fffu + ((v.u >> 16) & 1u);
    return (short)(r >> 16);
}

__device__ __forceinline__ bf16x8 cvt8(const float4& a, const float4& b) {
    bf16x8 t;
    t[0] = f2bf(a.x); t[1] = f2bf(a.y); t[2] = f2bf(a.z); t[3] = f2bf(a.w);
    t[4] = f2bf(b.x); t[5] = f2bf(b.y); t[6] = f2bf(b.z); t[7] = f2bf(b.w);
    return t;
}

// Block = 256 threads (4 waves), one channel c, 256 consecutive n-rows.
// Wave w handles rows [n0 + 64w, n0 + 64w + 64) in 4 chunks of 16.
// MFMA 16x16x32 bf16:
//   A frag: lane holds A[m = lane&15][k = (lane>>4)*8 + j], j=0..7 (contig)
//   B frag: lane holds B[k = (lane>>4)*8 + j][n = lane&15]  (W row-contig)
//   C/D:    lane,reg r -> D[row = (lane>>4)*4 + r][col = lane&15]
__global__ __launch_bounds__(256) void dw_mfma(
    const float* __restrict__ x, const float* __restrict__ W,
    const float* __restrict__ bias, float* __restrict__ out)
{
    const int bx   = blockIdx.x;
    const int c    = bx & (C_ - 1);
    const int nseg = bx >> 8;            // 0..15, 256 rows each
    const int tid  = threadIdx.x;
    const int wave = tid >> 6;
    const int lane = tid & 63;
    const int lr   = lane & 15;          // tile row (A) / tile col (B, D)
    const int kq   = lane >> 4;          // k-quad

    // ---- Load W_c fragments (held in registers for the whole block) ----
    bf16x8 bfrag[8][2];
    float  bv[8];
    const float* Wc = W + c * (HO_ * HI_);
    #pragma unroll
    for (int ot = 0; ot < 8; ++ot) {
        const int o = ot * 16 + lr;
        const float* wr = Wc + o * HI_ + kq * 8;
        #pragma unroll
        for (int kb = 0; kb < 2; ++kb) {
            const float4 w0 = *reinterpret_cast<const float4*>(wr + 32 * kb);
            const float4 w1 = *reinterpret_cast<const float4*>(wr + 32 * kb + 4);
            bfrag[ot][kb] = cvt8(w0, w1);
        }
        bv[ot] = bias[c * HO_ + o];
    }

    const int n_wave = nseg * 256 + wave * 64;

    #pragma unroll
    for (int ch = 0; ch < 4; ++ch) {
        const int n1 = n_wave + ch * 16;

        // ---- A fragments: 16 rows of x, direct global load + cvt ----
        const float* xr = x + ((long)(n1 + lr) * C_ + c) * HI_ + kq * 8;
        bf16x8 afrag[2];
        #pragma unroll
        for (int kb = 0; kb < 2; ++kb) {
            const float4 a0 = *reinterpret_cast<const float4*>(xr + 32 * kb);
            const float4 a1 = *reinterpret_cast<const float4*>(xr + 32 * kb + 4);
            afrag[kb] = cvt8(a0, a1);
        }

        // ---- MFMA: 8 o-tiles x 2 k-steps ----
        f32x4 acc[8];
        #pragma unroll
        for (int ot = 0; ot < 8; ++ot) acc[ot] = (f32x4){0.f, 0.f, 0.f, 0.f};
        #pragma unroll
        for (int kb = 0; kb < 2; ++kb) {
            #pragma unroll
            for (int ot = 0; ot < 8; ++ot) {
                acc[ot] = __builtin_amdgcn_mfma_f32_16x16x32_bf16(
                    afrag[kb], bfrag[ot][kb], acc[ot], 0, 0, 0);
            }
        }

        // ---- Epilogue: +bias, store (16 contiguous floats per lane-group) ----
        float* orow = out + ((long)(n1 + kq * 4) * C_ + c) * HO_ + lr;
        #pragma unroll
        for (int r = 0; r < 4; ++r) {
            #pragma unroll
            for (int ot = 0; ot < 8; ++ot) {
                orow[(long)r * (C_ * HO_) + ot * 16] = acc[ot][r] + bv[ot];
            }
        }
    }
}

extern "C" void kernel_launch(void* const* d_in, const int* in_sizes, int n_in,
                              void* d_out, int out_size, void* d_ws, size_t ws_size,
                              hipStream_t stream) {
    const float* x  = (const float*)d_in[0];
    const float* W  = (const float*)d_in[1];
    const float* b  = (const float*)d_in[2];
    float* out      = (float*)d_out;
    const int blocks = C_ * (N_ / 256);   // 4096
    dw_mfma<<<dim3(blocks), dim3(256), 0, stream>>>(x, W, b, out);
}